// Round 5
// baseline (428.678 us; speedup 1.0000x reference)
//
#include <hip/hip_runtime.h>
#include <stdint.h>

typedef unsigned short u16;
typedef __bf16 bf16x8 __attribute__((ext_vector_type(8)));
typedef float f32x16 __attribute__((ext_vector_type(16)));
typedef unsigned short u16x8 __attribute__((ext_vector_type(8)));
typedef unsigned short u16x4 __attribute__((ext_vector_type(4)));

#define B_BATCH 8
#define S_LEN   2048
#define D_DIM   1024
#define U_DIM   1024

#define BM 128
#define BN 128
#define BK 64

__device__ __forceinline__ float bf2f(u16 h) {
    union { unsigned u; float f; } c; c.u = ((unsigned)h) << 16; return c.f;
}
__device__ __forceinline__ u16 f2bf(float f) {
    union { float f; unsigned u; } c; c.f = f;
    unsigned r = c.u + 0x7fffu + ((c.u >> 16) & 1u);
    return (u16)(r >> 16);
}

__device__ __forceinline__ void cp16(u16* lds, const u16* g) {
    __builtin_amdgcn_global_load_lds((__attribute__((address_space(1))) void*)g,
                                     (__attribute__((address_space(3))) void*)lds,
                                     16, 0, 0);
}

// Shared 128x128xK K-loop, now on mfma_f32_32x32x16_bf16 (2x2 per wave).
// A-frag: m = lane&31, k-octet = ks*2 + (lane>>5). XOR bank swizzle as before.
__device__ __forceinline__ void gemm_core(
    const u16* __restrict__ A, int lda,
    const u16* __restrict__ Bt, int ldb,
    int m0, int n0, int K,
    u16* As, u16* Bs, int tid, f32x16 acc[2][2])
{
    const int lane = tid & 63;
    const int wm = ((tid >> 6) >> 1) * 64;
    const int wn = ((tid >> 6) & 1) * 64;
    const int c32 = lane & 31;
    const int h   = lane >> 5;
    const int sw  = c32 & 7;          // == row&7 for all fragment rows

    for (int k0 = 0; k0 < K; k0 += BK) {
        __syncthreads();
        #pragma unroll
        for (int s = 0; s < 4; ++s) {
            const int c = tid + 256 * s;
            const int r = c >> 3;
            const int q = (c & 7) ^ ((c >> 3) & 7);
            cp16(As + c * 8, A + (long long)(m0 + r) * lda + k0 + q * 8);
            cp16(Bs + c * 8, Bt + (long long)(n0 + r) * ldb + k0 + q * 8);
        }
        __syncthreads();

        #pragma unroll
        for (int ks = 0; ks < 4; ++ks) {
            const int ko = ks * 2 + h;       // this lane's k-octet (0..7)
            bf16x8 af[2], bfr[2];
            #pragma unroll
            for (int i = 0; i < 2; ++i)
                af[i] = *(const bf16x8*)(As + (wm + i * 32 + c32) * BK + ((ko ^ sw) * 8));
            #pragma unroll
            for (int j = 0; j < 2; ++j)
                bfr[j] = *(const bf16x8*)(Bs + (wn + j * 32 + c32) * BK + ((ko ^ sw) * 8));
            #pragma unroll
            for (int i = 0; i < 2; ++i)
                #pragma unroll
                for (int j = 0; j < 2; ++j)
                    acc[i][j] = __builtin_amdgcn_mfma_f32_32x32x16_bf16(af[i], bfr[j], acc[i][j], 0, 0, 0);
        }
    }
}

// z-pinned (z = lid&7 -> XCD) + m-panel swizzle for L2 locality
__device__ __forceinline__ void swizzle_mnz(int ph, int& mi, int& ni, int& z) {
    const int lid = blockIdx.x + gridDim.x * (blockIdx.y + gridDim.y * blockIdx.z);
    z = lid & 7;
    const int t = lid >> 3;
    const int ntn = gridDim.x;
    const int panel = t / (ph * ntn);
    const int r = t - panel * (ph * ntn);
    mi = panel * ph + (r % ph);
    ni = r / ph;
}

// ---------------- kernel 1: prep (x cvt, W transposes, rowsum zero) --------
__global__ __launch_bounds__(256) void prep(
    const float* __restrict__ x, u16* __restrict__ xb,
    const float* __restrict__ Wq, const float* __restrict__ Wk,
    const float* __restrict__ Wv, u16* __restrict__ WT,
    float* __restrict__ rowsum)
{
    __shared__ u16 tile[32][33];
    const int b = blockIdx.x;
    const int tid = threadIdx.x;
    if (b < 16384) {
        const int i = b * 256 + tid;
        float4 v = ((const float4*)x)[i];
        ushort4 o;
        o.x = f2bf(v.x); o.y = f2bf(v.y); o.z = f2bf(v.z); o.w = f2bf(v.w);
        ((ushort4*)xb)[i] = o;
    } else if (b < 16384 + 3072) {
        const int b2 = b - 16384;
        const int w = b2 >> 10;
        const int idx = b2 & 1023;
        const float* src = (w == 0) ? Wq : (w == 1) ? Wk : Wv;
        u16* dst = WT + (size_t)w * D_DIM * U_DIM;
        const int c0 = (idx & 31) * 32, rr0 = (idx >> 5) * 32;
        const int tx = tid & 31, ty = tid >> 5;
        #pragma unroll
        for (int i = 0; i < 32; i += 8)
            tile[ty + i][tx] = f2bf(src[(long long)(rr0 + ty + i) * U_DIM + c0 + tx]);
        __syncthreads();
        #pragma unroll
        for (int i = 0; i < 32; i += 8)
            dst[(long long)(c0 + ty + i) * D_DIM + rr0 + tx] = tile[tx][ty + i];
    } else {
        const int i = (b - 16384 - 3072) * 256 + tid;   // < 4096, exact
        float4 z4; z4.x = z4.y = z4.z = z4.w = 0.0f;
        ((float4*)rowsum)[i] = z4;
    }
}

// ------------- kernel 2: fused QKV projection (V written transposed) -------
__global__ __launch_bounds__(256, 2) void qkv_proj(
    const u16* __restrict__ xb, const u16* __restrict__ WT,
    const float* __restrict__ bq, const float* __restrict__ bk,
    const float* __restrict__ bv,
    u16* __restrict__ Q, u16* __restrict__ Ko, u16* __restrict__ VT)
{
    __shared__ __align__(16) u16 smem[BM * BK * 2];   // As|Bs, reused as T[128][128]
    u16* As = smem;
    u16* Bs = smem + BM * BK;

    const int tgt = blockIdx.x >> 3;
    const int n0 = (blockIdx.x & 7) * BN;
    const int m0 = blockIdx.y * BM;
    const int tid = threadIdx.x;
    const int lane = tid & 63;
    const int wm = ((tid >> 6) >> 1) * 64;
    const int wn = ((tid >> 6) & 1) * 64;
    const int c32 = lane & 31;
    const int h   = lane >> 5;

    const u16* Bt = WT + (size_t)tgt * (D_DIM * U_DIM);
    const float* bias = (tgt == 0) ? bq : (tgt == 1) ? bk : bv;

    f32x16 acc[2][2] = {};
    gemm_core(xb, D_DIM, Bt, D_DIM, m0, n0, D_DIM, As, Bs, tid, acc);

    if (tgt < 2) {
        u16* C = (tgt == 0) ? Q : Ko;
        #pragma unroll
        for (int j = 0; j < 2; ++j) {
            const int n = n0 + wn + j * 32 + c32;
            const float bvv = bias[n];
            #pragma unroll
            for (int i = 0; i < 2; ++i) {
                const int base = m0 + wm + i * 32 + 4 * h;
                #pragma unroll
                for (int rg = 0; rg < 4; ++rg)
                    #pragma unroll
                    for (int t = 0; t < 4; ++t)
                        C[(long long)(base + rg * 8 + t) * U_DIM + n] =
                            f2bf(acc[i][j][rg * 4 + t] + bvv);
            }
        }
    } else {
        // V: transpose 128x128 tile through LDS, write VT[u][s] coalesced.
        __syncthreads();   // done with As/Bs K-loop reads
        #pragma unroll
        for (int j = 0; j < 2; ++j) {
            const int cl = wn + j * 32 + c32;
            const float bvv = bias[n0 + cl];
            #pragma unroll
            for (int i = 0; i < 2; ++i) {
                #pragma unroll
                for (int rg = 0; rg < 4; ++rg) {
                    const int rb4 = wm + i * 32 + 4 * h + 8 * rg; // rows rb4..rb4+3
                    u16x4 pk;
                    #pragma unroll
                    for (int t = 0; t < 4; ++t) pk[t] = f2bf(acc[i][j][rg * 4 + t] + bvv);
                    const int idx = cl * 128 + (((rb4 >> 3) ^ (cl & 15)) * 8) + (rb4 & 7);
                    *(u16x4*)(smem + idx) = pk;
                }
            }
        }
        __syncthreads();
        const int zb = m0 >> 11;
        const int s0 = m0 & 2047;
        u16* VTg = VT + (size_t)zb * ((size_t)S_LEN * U_DIM);
        #pragma unroll
        for (int s = 0; s < 8; ++s) {
            const int cid = tid + 256 * s;   // 2048 chunks: col(128) x m8(16)
            const int cl = cid >> 4;
            const int m8 = cid & 15;
            u16x8 v = *(const u16x8*)(smem + cl * 128 + ((m8 ^ (cl & 15)) * 8));
            *(u16x8*)(VTg + (size_t)(n0 + cl) * S_LEN + s0 + m8 * 8) = v;
        }
    }
}

// ------ kernel 3: scores + exp + mask + rowsum (softmax w/o max-sub) -------
__global__ __launch_bounds__(256, 2) void scores_exp(
    const u16* __restrict__ Qb, const u16* __restrict__ Kb,
    u16* __restrict__ E, const int* __restrict__ mask,
    float* __restrict__ rowsum, int ph)
{
    __shared__ __align__(16) u16 smem[BM * BK * 2];
    u16* As = smem;
    u16* Bs = smem + BM * BK;

    int mi, ni, z;
    swizzle_mnz(ph, mi, ni, z);
    const int m0 = mi * BM, n0 = ni * BN;
    const long long SU = (long long)S_LEN * U_DIM;
    const long long SS = (long long)S_LEN * S_LEN;

    const int tid = threadIdx.x;
    const int lane = tid & 63;
    const int wm = ((tid >> 6) >> 1) * 64;
    const int wn = ((tid >> 6) & 1) * 64;
    const int c32 = lane & 31;
    const int h   = lane >> 5;

    f32x16 acc[2][2] = {};
    gemm_core(Qb + (long long)z * SU, U_DIM, Kb + (long long)z * SU, U_DIM,
              m0, n0, U_DIM, As, Bs, tid, acc);

    u16* Eg = E + (long long)z * SS;
    const int* mrow = mask + (size_t)z * S_LEN;

    int mj[2];
    #pragma unroll
    for (int j = 0; j < 2; ++j) mj[j] = mrow[n0 + wn + j * 32 + c32];

    #pragma unroll
    for (int i = 0; i < 2; ++i) {
        const int base = m0 + wm + i * 32 + 4 * h;
        #pragma unroll
        for (int rg = 0; rg < 4; ++rg) {
            #pragma unroll
            for (int t = 0; t < 4; ++t) {
                const int row = base + rg * 8 + t;
                const int mi_ = mrow[row];
                float partial = 0.0f;
                #pragma unroll
                for (int j = 0; j < 2; ++j) {
                    // m_i=0 row: uniform -1e4 shift cancels in softmax.
                    // m_i=1 & m_j=0: exactly 0 (ref exp(-1e4+s) == 0 in fp32).
                    float e = (mi_ && !mj[j]) ? 0.0f
                            : __expf(acc[i][j][rg * 4 + t] * 0.03125f);
                    const u16 hh = f2bf(e);
                    Eg[(long long)row * S_LEN + n0 + wn + j * 32 + c32] = hh;
                    partial += bf2f(hh);   // sum what PV will actually read
                }
                // reduce across the 32-lane half (h=0/h=1 are different rows)
                partial += __shfl_xor(partial, 1, 32);
                partial += __shfl_xor(partial, 2, 32);
                partial += __shfl_xor(partial, 4, 32);
                partial += __shfl_xor(partial, 8, 32);
                partial += __shfl_xor(partial, 16, 32);
                if (c32 == 0)
                    atomicAdd(&rowsum[(size_t)z * S_LEN + row], partial);
            }
        }
    }
}

// --------------- kernel 4: out = (E @ V) / rowsum, fp32 out ----------------
__global__ __launch_bounds__(256, 2) void pv_gemm(
    const u16* __restrict__ E, const u16* __restrict__ VT,
    float* __restrict__ out, const float* __restrict__ rowsum, int ph)
{
    __shared__ __align__(16) u16 smem[BM * BK * 2];
    u16* As = smem;
    u16* Bs = smem + BM * BK;

    int mi, ni, z;
    swizzle_mnz(ph, mi, ni, z);
    const int m0 = mi * BM, n0 = ni * BN;
    const long long SU = (long long)S_LEN * U_DIM;
    const long long SS = (long long)S_LEN * S_LEN;

    const int tid = threadIdx.x;
    const int lane = tid & 63;
    const int wm = ((tid >> 6) >> 1) * 64;
    const int wn = ((tid >> 6) & 1) * 64;
    const int c32 = lane & 31;
    const int h   = lane >> 5;

    f32x16 acc[2][2] = {};
    gemm_core(E + (long long)z * SS, S_LEN, VT + (long long)z * SU, S_LEN,
              m0, n0, S_LEN, As, Bs, tid, acc);

    float* Cg = out + (long long)z * SU;
    const float* rs = rowsum + (size_t)z * S_LEN;

    #pragma unroll
    for (int i = 0; i < 2; ++i) {
        const int base = m0 + wm + i * 32 + 4 * h;
        #pragma unroll
        for (int rg = 0; rg < 4; ++rg) {
            #pragma unroll
            for (int t = 0; t < 4; ++t) {
                const int row = base + rg * 8 + t;
                const float inv = 1.0f / rs[row];
                #pragma unroll
                for (int j = 0; j < 2; ++j)
                    Cg[(long long)row * U_DIM + n0 + wn + j * 32 + c32] =
                        acc[i][j][rg * 4 + t] * inv;
            }
        }
    }
}

extern "C" void kernel_launch(void* const* d_in, const int* in_sizes, int n_in,
                              void* d_out, int out_size, void* d_ws, size_t ws_size,
                              hipStream_t stream)
{
    (void)in_sizes; (void)n_in; (void)out_size; (void)ws_size;
    const float* x    = (const float*)d_in[0];
    const int*   mask = (const int*)d_in[1];
    const float* Wq   = (const float*)d_in[2];
    const float* bq   = (const float*)d_in[3];
    const float* Wk   = (const float*)d_in[4];
    const float* bk   = (const float*)d_in[5];
    const float* Wv   = (const float*)d_in[6];
    const float* bv   = (const float*)d_in[7];

    const size_t DU  = (size_t)D_DIM * U_DIM;
    const size_t BSU = (size_t)B_BATCH * S_LEN * U_DIM;

    // ws layout (u16 units): Qb | Kb | VTb | WT(x3) | rowsum | E (aliases xb)
    u16* ws  = (u16*)d_ws;
    u16* Qb  = ws;
    u16* Kb  = Qb + BSU;
    u16* VTb = Kb + BSU;
    u16* WT  = VTb + BSU;
    float* rowsum = (float*)(WT + 3 * DU);
    u16* E   = (u16*)(rowsum + (size_t)B_BATCH * S_LEN);
    u16* xb  = E;   // alias: xb dead before E is written

    dim3 blk(256);

    prep<<<dim3(16384 + 3072 + 16), blk, 0, stream>>>(x, xb, Wq, Wk, Wv, WT, rowsum);

    qkv_proj<<<dim3(24, 128), blk, 0, stream>>>(xb, WT, bq, bk, bv, Qb, Kb, VTb);

    scores_exp<<<dim3(S_LEN / BN, S_LEN / BM, B_BATCH), blk, 0, stream>>>(
        Qb, Kb, E, mask, rowsum, 8);

    pv_gemm<<<dim3(U_DIM / BN, S_LEN / BM, B_BATCH), blk, 0, stream>>>(
        E, VTb, (float*)d_out, rowsum, 16);
}